// Round 10
// baseline (84.371 us; speedup 1.0000x reference)
//
#include <hip/hip_runtime.h>
#include <math.h>

#define BB 2
#define CC 192
#define NN 16384
#define KK 16
#define COUT 192
#define MM (BB * NN)          // 32768 points
#define KDIM (2 * CC)         // 384 = GEMM K
#define EPSF 1e-5f
#define NGB 256               // fused grid (partial-sum rows)

typedef __attribute__((ext_vector_type(8))) short short8;
typedef __attribute__((ext_vector_type(4))) float f32x4;

#define AS1P const __attribute__((address_space(1))) void*
#define AS3P __attribute__((address_space(3))) void*

static __device__ __forceinline__ float bf16_to_f32(unsigned int u16) {
    return __uint_as_float(u16 << 16);
}
static __device__ __forceinline__ float bf16hi_to_f32(unsigned int u) {
    return __uint_as_float(u & 0xffff0000u);
}
static __device__ __forceinline__ unsigned short f32_to_bf16(float f) {
    unsigned int u = __float_as_uint(f);
    unsigned int r = (u + 0x7fffu + ((u >> 16) & 1u)) >> 16;  // RNE
    return (unsigned short)r;
}
static __device__ __forceinline__ float gelu_exact(float v) {
    return 0.5f * v * (1.0f + erff(v * 0.70710678118654752440f));
}

// ---------------------------------------------------------------------------
// Kernel 1 (k_prep): blockIdx < 3072 -> transpose+cast x [B,C,N] f32 ->
// xt [B,N,C] bf16 (flat layout, reverted from round-9 chunking: no gain).
// blockIdx >= 3072 -> cast W -> bf16.
// ---------------------------------------------------------------------------
#define TRB (512 * 3 * BB)   // 3072 transpose blocks
__global__ __launch_bounds__(256) void k_prep(const float* __restrict__ x,
                                              unsigned int* __restrict__ xt32,
                                              const float* __restrict__ W,
                                              unsigned short* __restrict__ Wb) {
    int bid = blockIdx.x;
    int t = threadIdx.x;
    if (bid >= TRB) {
        int wb = bid - TRB;                       // 0..71
        int base = wb * 1024 + t * 4;
        float4 v = *(const float4*)(W + base);
        uint2 o;
        o.x = (unsigned int)f32_to_bf16(v.x) | ((unsigned int)f32_to_bf16(v.y) << 16);
        o.y = (unsigned int)f32_to_bf16(v.z) | ((unsigned int)f32_to_bf16(v.w) << 16);
        *(uint2*)(Wb + base) = o;
        return;
    }
    __shared__ float tile[64][33];
    int nb = bid & 511;
    int rest = bid >> 9;
    int cb = rest % 3;
    int b = rest / 3;
    int n0 = nb * 32, c0 = cb * 64;
    int tx = t & 31, ty = t >> 5;  // (32,8)
    #pragma unroll
    for (int j = 0; j < 64; j += 8)
        tile[ty + j][tx] = x[((size_t)b * CC + (c0 + ty + j)) * NN + n0 + tx];
    __syncthreads();
    #pragma unroll
    for (int j = 0; j < 32; j += 8) {
        int n = n0 + ty + j;
        unsigned int w = (unsigned int)f32_to_bf16(tile[2 * tx][ty + j]) |
                         ((unsigned int)f32_to_bf16(tile[2 * tx + 1][ty + j]) << 16);
        xt32[(((size_t)b * NN + n) * CC + c0) / 2 + tx] = w;
    }
}

// ---------------------------------------------------------------------------
// Kernel 2 (k_fused): per-block gather -> xcat (own 128 rows, L1/L2-hot) ->
// MFMA GEMM -> h + psum. No cross-block deps, no grid sync. LDS 48 KB ->
// 3 blocks/CU (24 waves/CU hides gather latency; round-3's 96KB-LDS fusion
// died at 1 block/CU). Gather: 2 passes x 64 pts, 8 thr/pt, 24 ch (3 uint4).
// ---------------------------------------------------------------------------
#define BMT 128
__global__ __launch_bounds__(512) void k_fused(const unsigned short* __restrict__ xt,
                                               const int* __restrict__ edge,
                                               const unsigned short* __restrict__ Wb,
                                               unsigned short* __restrict__ xcat,
                                               unsigned short* __restrict__ h,
                                               float* __restrict__ psum,
                                               float* __restrict__ psum2) {
    __shared__ __align__(16) char ldsA[BMT * 128];    // 16 KB (reused for reduce)
    __shared__ __align__(16) char ldsB[COUT * 128];   // 24 KB
    __shared__ unsigned short sjw[BMT * KK], siw[BMT * KK];  // 8 KB (idx < 16384)
    int t = threadIdx.x;
    int m0 = blockIdx.x * BMT;
    int b = m0 >> 14, n0 = m0 & (NN - 1);

    // stage edge indices as ushort (coalesced int reads)
    {
        const int* ej = edge + ((size_t)b * NN + n0) * KK;
        const int* ei = edge + ((size_t)(BB + b) * NN + n0) * KK;
        for (int u = t; u < BMT * KK; u += 512) {
            sjw[u] = (unsigned short)ej[u];
            siw[u] = (unsigned short)ei[u];
        }
    }
    __syncthreads();

    // ---- phase G: gather + max-relative -> xcat rows m0..m0+127 ----
    {
        int q = t & 7;                                // 24-ch slot
        const uint4* rowb = (const uint4*)(xt + (size_t)b * NN * CC);  // 24 uint4/row
        uint4* xc4 = (uint4*)xcat;
        #pragma unroll
        for (int g2 = 0; g2 < 2; ++g2) {
            int p = g2 * 64 + (t >> 3);               // point 0..127
            float mx[24];
            #pragma unroll
            for (int c = 0; c < 24; ++c) mx[c] = -INFINITY;
            #pragma unroll
            for (int k = 0; k < KK; ++k) {
                int rj = sjw[p * KK + k];
                int ri = siw[p * KK + k];
                const uint4* pj = rowb + (size_t)rj * 24 + q * 3;
                const uint4* pi = rowb + (size_t)ri * 24 + q * 3;
                #pragma unroll
                for (int s = 0; s < 3; ++s) {
                    uint4 vj = pj[s], vi = pi[s];
                    const unsigned int dj[4] = {vj.x, vj.y, vj.z, vj.w};
                    const unsigned int di[4] = {vi.x, vi.y, vi.z, vi.w};
                    #pragma unroll
                    for (int d = 0; d < 4; ++d) {
                        mx[s * 8 + 2 * d]     = fmaxf(mx[s * 8 + 2 * d],
                            bf16_to_f32(dj[d] & 0xffffu) - bf16_to_f32(di[d] & 0xffffu));
                        mx[s * 8 + 2 * d + 1] = fmaxf(mx[s * 8 + 2 * d + 1],
                            bf16hi_to_f32(dj[d]) - bf16hi_to_f32(di[d]));
                    }
                }
            }
            const uint4* px = rowb + (size_t)(n0 + p) * 24 + q * 3;
            size_t orow = (size_t)(m0 + p) * 48 + q * 6;
            #pragma unroll
            for (int s = 0; s < 3; ++s) {
                uint4 xsv = px[s];
                const unsigned int dx[4] = {xsv.x, xsv.y, xsv.z, xsv.w};
                uint4 o0, o1;
                o0.x = (dx[0] & 0xffffu) | ((unsigned int)f32_to_bf16(mx[s * 8 + 0]) << 16);
                o0.y = (dx[0] >> 16)     | ((unsigned int)f32_to_bf16(mx[s * 8 + 1]) << 16);
                o0.z = (dx[1] & 0xffffu) | ((unsigned int)f32_to_bf16(mx[s * 8 + 2]) << 16);
                o0.w = (dx[1] >> 16)     | ((unsigned int)f32_to_bf16(mx[s * 8 + 3]) << 16);
                o1.x = (dx[2] & 0xffffu) | ((unsigned int)f32_to_bf16(mx[s * 8 + 4]) << 16);
                o1.y = (dx[2] >> 16)     | ((unsigned int)f32_to_bf16(mx[s * 8 + 5]) << 16);
                o1.z = (dx[3] & 0xffffu) | ((unsigned int)f32_to_bf16(mx[s * 8 + 6]) << 16);
                o1.w = (dx[3] >> 16)     | ((unsigned int)f32_to_bf16(mx[s * 8 + 7]) << 16);
                xc4[orow + 2 * s]     = o0;
                xc4[orow + 2 * s + 1] = o1;
            }
        }
    }
    __syncthreads();   // drains vmcnt -> xcat writes visible to our gll reads

    // ---- phase M: MFMA GEMM on own rows (xcat L1/L2-hot) ----
    int w = t >> 6, l = t & 63, lo = l & 15, q4 = l >> 4;
    int lr = l >> 3, lc = l & 7;   // staging: row-in-8-group, chunk
    f32x4 acc[12];
    #pragma unroll
    for (int i = 0; i < 12; ++i) acc[i] = (f32x4){0.f, 0.f, 0.f, 0.f};
    int rA = w * 16 + lo;

    for (int ks = 0; ks < KDIM / 64; ++ks) {
        int k0 = ks * 64;
        if (ks) __syncthreads();
        #pragma unroll
        for (int e = 0; e < 2; ++e) {
            int r = w * 16 + e * 8 + lr;
            int cg = lc ^ (r & 7);
            const unsigned short* gp = xcat + (size_t)(m0 + r) * KDIM + k0 + cg * 8;
            __builtin_amdgcn_global_load_lds((AS1P)gp, (AS3P)(ldsA + w * 2048 + e * 1024), 16, 0, 0);
        }
        #pragma unroll
        for (int e = 0; e < 3; ++e) {
            int r = w * 24 + e * 8 + lr;
            int cg = lc ^ (r & 7);
            const unsigned short* gp = Wb + (size_t)r * KDIM + k0 + cg * 8;
            __builtin_amdgcn_global_load_lds((AS1P)gp, (AS3P)(ldsB + w * 3072 + e * 1024), 16, 0, 0);
        }
        __syncthreads();
        #pragma unroll
        for (int kh = 0; kh < 2; ++kh) {
            int cb = kh * 64 + q4 * 16;
            short8 a = *(const short8*)(ldsA + rA * 128 + (cb ^ ((rA & 7) << 4)));
            #pragma unroll
            for (int ot = 0; ot < 12; ++ot) {
                int rB = ot * 16 + lo;
                short8 bf = *(const short8*)(ldsB + rB * 128 + (cb ^ ((rB & 7) << 4)));
                acc[ot] = __builtin_amdgcn_mfma_f32_16x16x32_bf16(a, bf, acc[ot], 0, 0, 0);
            }
        }
    }
    __syncthreads();  // all waves done with ldsA before the reduce overlay

    // epilogue: h (bf16) + per-wave BN sums. C/D: o=lane&15, m=q4*4+reg
    float* reds = (float*)ldsA;              // [8][COUT]
    float* reds2 = reds + 8 * COUT;          // [8][COUT]
    int mrow = m0 + w * 16 + q4 * 4;
    #pragma unroll
    for (int ot = 0; ot < 12; ++ot) {
        int o = ot * 16 + lo;
        float s = 0.f, s2 = 0.f;
        #pragma unroll
        for (int r = 0; r < 4; ++r) {
            float v = acc[ot][r];
            h[(size_t)(mrow + r) * COUT + o] = f32_to_bf16(v);
            s += v;
            s2 += v * v;
        }
        s += __shfl_xor(s, 16);  s2 += __shfl_xor(s2, 16);
        s += __shfl_xor(s, 32);  s2 += __shfl_xor(s2, 32);
        if (q4 == 0) {
            reds[w * COUT + o] = s;
            reds2[w * COUT + o] = s2;
        }
    }
    __syncthreads();
    if (t < COUT) {
        float a = 0.f, a2 = 0.f;
        #pragma unroll
        for (int w8 = 0; w8 < 8; ++w8) {
            a += reds[w8 * COUT + t];
            a2 += reds2[w8 * COUT + t];
        }
        psum[blockIdx.x * COUT + t] = a;
        psum2[blockIdx.x * COUT + t] = a2;
    }
}

// ---------------------------------------------------------------------------
// Kernel 3 (k_bn): parallel partial reduce. 24 blocks x 256 threads.
// ---------------------------------------------------------------------------
__global__ __launch_bounds__(256) void k_bn(const float* __restrict__ psum,
                                            const float* __restrict__ psum2,
                                            const float* __restrict__ gamma,
                                            const float* __restrict__ beta,
                                            float* __restrict__ sc_sh) {
    __shared__ float red[2][32][8];
    int t = threadIdx.x;
    int ch = t & 7, rr = t >> 3;
    int o = blockIdx.x * 8 + ch;
    float a = 0.f, a2 = 0.f;
    for (int r = rr; r < NGB; r += 32) {
        a += psum[r * COUT + o];
        a2 += psum2[r * COUT + o];
    }
    red[0][rr][ch] = a;
    red[1][rr][ch] = a2;
    __syncthreads();
    if (t < 8) {
        float s = 0.f, s2 = 0.f;
        #pragma unroll
        for (int i = 0; i < 32; ++i) { s += red[0][i][t]; s2 += red[1][i][t]; }
        int oo = blockIdx.x * 8 + t;
        float inv_m = 1.0f / (float)MM;
        float mean = s * inv_m;
        float var = s2 * inv_m - mean * mean;
        float sc = gamma[oo] * rsqrtf(var + EPSF);
        sc_sh[oo] = sc;
        sc_sh[COUT + oo] = beta[oo] - mean * sc;
    }
}

// ---------------------------------------------------------------------------
// Kernel 4 (k_out): BN apply + exact GELU + transpose h [m][o] -> out [B,O,N].
// uint4 h-loads, float4 out-stores.
// ---------------------------------------------------------------------------
__global__ __launch_bounds__(256) void k_out(const unsigned short* __restrict__ h,
                                             const float* __restrict__ sc_sh,
                                             float* __restrict__ out) {
    __shared__ float tile[64][36];
    int b = blockIdx.z;
    int n0 = blockIdx.x * 64;
    int o0 = blockIdx.y * 32;
    int t = threadIdx.x;
    {
        int r = t >> 2, c4 = t & 3;
        uint4 hv = *(const uint4*)(h + ((size_t)b * NN + n0 + r) * COUT + o0 + c4 * 8);
        const unsigned int d[4] = {hv.x, hv.y, hv.z, hv.w};
        #pragma unroll
        for (int e = 0; e < 4; ++e) {
            int oc = c4 * 8 + 2 * e;
            float v0 = bf16_to_f32(d[e] & 0xffffu) * sc_sh[o0 + oc] + sc_sh[COUT + o0 + oc];
            float v1 = bf16hi_to_f32(d[e]) * sc_sh[o0 + oc + 1] + sc_sh[COUT + o0 + oc + 1];
            tile[r][oc] = gelu_exact(v0);
            tile[r][oc + 1] = gelu_exact(v1);
        }
    }
    __syncthreads();
    int o = t >> 3, q = t & 7;
    #pragma unroll
    for (int it = 0; it < 2; ++it) {
        int nn = q * 4 + it * 32;
        float4 v = {tile[nn][o], tile[nn + 1][o], tile[nn + 2][o], tile[nn + 3][o]};
        *(float4*)(out + ((size_t)b * COUT + o0 + o) * NN + n0 + nn) = v;
    }
}

// ---------------------------------------------------------------------------
extern "C" void kernel_launch(void* const* d_in, const int* in_sizes, int n_in,
                              void* d_out, int out_size, void* d_ws, size_t ws_size,
                              hipStream_t stream) {
    const float* x = (const float*)d_in[0];
    const float* W = (const float*)d_in[1];
    // d_in[2] = b_conv: cancels in training-mode BN
    const float* gamma = (const float*)d_in[3];
    const float* beta = (const float*)d_in[4];
    const int* edge = (const int*)d_in[5];
    float* out = (float*)d_out;

    char* ws = (char*)d_ws;
    unsigned short* xt = (unsigned short*)ws;                 // [M][C] bf16
    ws += (size_t)MM * CC * 2;
    unsigned short* xcat = (unsigned short*)ws;               // [M][2C] bf16
    ws += (size_t)MM * KDIM * 2;
    unsigned short* Wb = (unsigned short*)ws;                 // [COUT][2C] bf16
    ws += (size_t)COUT * KDIM * 2;
    unsigned short* h = (unsigned short*)ws;                  // [M][COUT] bf16
    ws += (size_t)MM * COUT * 2;
    float* psum = (float*)ws;                                 // [NGB][COUT]
    ws += (size_t)NGB * COUT * sizeof(float);
    float* psum2 = (float*)ws;                                // [NGB][COUT]
    ws += (size_t)NGB * COUT * sizeof(float);
    float* sc_sh = (float*)ws;                                // [2*COUT]

    k_prep<<<TRB + 72, 256, 0, stream>>>(x, (unsigned int*)xt, W, Wb);

    k_fused<<<MM / BMT, 512, 0, stream>>>(xt, edge, Wb, xcat, h, psum, psum2);

    k_bn<<<24, 256, 0, stream>>>(psum, psum2, gamma, beta, sc_sh);

    dim3 ogrid(NN / 64, COUT / 32, BB);
    k_out<<<ogrid, dim3(256), 0, stream>>>(h, sc_sh, out);
}